// Round 3
// baseline (10.473 us; speedup 1.0000x reference)
//
#include <hip/hip_runtime.h>
#include <math.h>

// BehlerG2 angular symmetry function, fused. One block per (b,n) row.
// Phase 1 stages 3 scalars per triple into LDS: {r2, bs=1-cos_theta, log2(w)}.
// Phase 2: 16 lane-groups of 16 (lane=eta e), accumulating
//   S[e,j] = sum_t 2^( r2_t * (-eta_e*log2e) + log2 w_t ) * bs_t^{2^j}
// with bs powers rebuilt by repeated squaring (3 muls) — LDS payload is
// 12 B/triple, read as one b128 + one b64 per PAIR of triples (t, t+16).
// Epilogue applies c_z = 2^(1±zeta).

#define T_TRIP 512
#define NPAIR  (T_TRIP / 2)
#define E_N 16

__global__ __launch_bounds__(256) void behler_g2_kernel(
    const float* __restrict__ r_ij, const float* __restrict__ r_ik,
    const float* __restrict__ r_jk, const float* __restrict__ mask,
    const float* __restrict__ etas, const float* __restrict__ zetas,
    float* __restrict__ out)
{
    __shared__ float4 RB[NPAIR];      // {r2(t), bs(t), r2(t+16), bs(t+16)}
    __shared__ float2 LW[NPAIR];      // {log2w(t), log2w(t+16)}
    __shared__ float  red[4][E_N][4]; // per-wave partial sums

    const int blk = blockIdx.x;            // flattened (b*N + n)
    const int tid = threadIdx.x;
    const size_t b2 = (size_t)blk * (T_TRIP / 2) + tid;  // float2 index

    const float z0 = zetas[0], z1 = zetas[1], z2 = zetas[2], z3 = zetas[3];
    const bool fastz = (z0 == 1.0f && z1 == 2.0f && z2 == 4.0f && z3 == 8.0f);
    const float PI_OVER_RC = 0.52359877559829887f;   // pi / 6
    const float LOG2E      = 1.4426950408889634f;

    // ---- Phase 1: vectorized loads, stage {r2, bs, lw} per triple ----
    const float2 va = ((const float2*)r_ij)[b2];
    const float2 vb = ((const float2*)r_ik)[b2];
    const float2 vc = ((const float2*)r_jk)[b2];
    const float2 vm = ((const float2*)mask)[b2];

    #pragma unroll
    for (int k = 0; k < 2; ++k) {
        int t = 2 * tid + k;
        float a = k ? va.y : va.x;
        float b = k ? vb.y : vb.x;
        float c = k ? vc.y : vc.x;
        float m = k ? vm.y : vm.x;
        float r2 = fmaf(a, a, fmaf(b, b, c * c));
        float fa  = (a < 6.0f) ? 0.5f * (__cosf(a * PI_OVER_RC) + 1.0f) : 0.0f;
        float fb  = (b < 6.0f) ? 0.5f * (__cosf(b * PI_OVER_RC) + 1.0f) : 0.0f;
        float fcv = (c < 6.0f) ? 0.5f * (__cosf(c * PI_OVER_RC) + 1.0f) : 0.0f;
        float w = m * fa * fb * fcv;                 // >= 0
        float ct = __fdividef(r2, 2.0f * a * b);
        float bs = 1.0f - ct;
        if (!fastz && m == 0.0f) bs = 0.0f;          // powf(neg,frac) guard
        float lw = __log2f(w);                       // w==0 -> -inf -> x==0

        int p    = (t >> 5) * 16 + (t & 15);         // pair index
        int slot = (t >> 4) & 1;                     // 0: t, 1: t+16
        ((float2*)&RB[p])[slot] = make_float2(r2, bs);   // ds_write_b64
        ((float*)&LW[p])[slot]  = lw;                    // ds_write_b32
    }
    __syncthreads();

    // ---- Phase 2: 16 groups of 16 lanes; lane = eta index e ----
    const int g = tid >> 4;          // group handles t == g (mod 16)
    const int e = tid & 15;
    const float me = -etas[e] * LOG2E;

    float acc0 = 0.0f, acc1 = 0.0f, acc2 = 0.0f, acc3 = 0.0f;
    if (fastz) {
        #pragma unroll
        for (int i = 0; i < NPAIR / 16; ++i) {
            float4 rb = RB[i * 16 + g];              // one b128
            float2 lw = LW[i * 16 + g];              // one b64
            float xa = exp2f(fmaf(rb.x, me, lw.x));
            float xb = exp2f(fmaf(rb.z, me, lw.y));
            float s1 = rb.y, s2 = s1 * s1, s4 = s2 * s2, s8 = s4 * s4;
            acc0 = fmaf(xa, s1, acc0);
            acc1 = fmaf(xa, s2, acc1);
            acc2 = fmaf(xa, s4, acc2);
            acc3 = fmaf(xa, s8, acc3);
            float u1 = rb.w, u2 = u1 * u1, u4 = u2 * u2, u8 = u4 * u4;
            acc0 = fmaf(xb, u1, acc0);
            acc1 = fmaf(xb, u2, acc1);
            acc2 = fmaf(xb, u4, acc2);
            acc3 = fmaf(xb, u8, acc3);
        }
    } else {
        #pragma unroll 1
        for (int i = 0; i < NPAIR / 16; ++i) {
            float4 rb = RB[i * 16 + g];
            float2 lw = LW[i * 16 + g];
            float xa = exp2f(fmaf(rb.x, me, lw.x));
            float xb = exp2f(fmaf(rb.z, me, lw.y));
            acc0 = fmaf(xa, powf(rb.y, z0), acc0) + xb * powf(rb.w, z0);
            acc1 = fmaf(xa, powf(rb.y, z1), acc1) + xb * powf(rb.w, z1);
            acc2 = fmaf(xa, powf(rb.y, z2), acc2) + xb * powf(rb.w, z2);
            acc3 = fmaf(xa, powf(rb.y, z3), acc3) + xb * powf(rb.w, z3);
        }
    }

    // reduce the 4 groups within each wave (lanes l, l+16, l+32, l+48)
    acc0 += __shfl_down(acc0, 32); acc0 += __shfl_down(acc0, 16);
    acc1 += __shfl_down(acc1, 32); acc1 += __shfl_down(acc1, 16);
    acc2 += __shfl_down(acc2, 32); acc2 += __shfl_down(acc2, 16);
    acc3 += __shfl_down(acc3, 32); acc3 += __shfl_down(acc3, 16);

    const int wave = tid >> 6;
    if ((tid & 63) < 16) {
        red[wave][e][0] = acc0;
        red[wave][e][1] = acc1;
        red[wave][e][2] = acc2;
        red[wave][e][3] = acc3;
    }
    __syncthreads();

    // ---- Epilogue: combine wave partials, apply 2^(1±zeta) ----
    if (tid < 128) {
        int ee = tid >> 3, z = tid & 7, j = z & 3;
        float s = red[0][ee][j] + red[1][ee][j] + red[2][ee][j] + red[3][ee][j];
        float zj = zetas[j];
        float coef = exp2f((z < 4) ? (1.0f - zj) : (1.0f + zj));
        out[(size_t)blk * 128 + tid] = coef * s;
    }
}

extern "C" void kernel_launch(void* const* d_in, const int* in_sizes, int n_in,
                              void* d_out, int out_size, void* d_ws, size_t ws_size,
                              hipStream_t stream) {
    const float* r_ij = (const float*)d_in[0];
    const float* r_ik = (const float*)d_in[1];
    const float* r_jk = (const float*)d_in[2];
    const float* mask = (const float*)d_in[3];
    const float* etas = (const float*)d_in[4];
    const float* zetas = (const float*)d_in[5];
    float* out = (float*)d_out;

    int nblk = out_size / 128;   // B*N rows, 128 outputs each
    behler_g2_kernel<<<nblk, 256, 0, stream>>>(r_ij, r_ik, r_jk, mask,
                                               etas, zetas, out);
}

// Round 4
// 9.804 us; speedup vs baseline: 1.0683x; 1.0683x over previous
//
#include <hip/hip_runtime.h>
#include <math.h>

// BehlerG2 angular symmetry function, fused. One block per (b,n) row,
// 512 threads (8 waves) -> 32 waves/CU occupancy and a halved per-block
// critical path vs the 256-thread variant.
// Phase 1: thread t computes triple t's {r2, p = w * bs^{zeta_j}} into LDS.
// Phase 2: 32 lane-groups of 16 (lane = eta e), 16 iters each:
//   S[e,j] += exp(-r2_t * eta_e) * p_j(t)
// Epilogue applies c_z = 2^(1±zeta) and writes 128 floats.

#define T_TRIP 512
#define E_N 16

__global__ __launch_bounds__(512, 8) void behler_g2_kernel(
    const float* __restrict__ r_ij, const float* __restrict__ r_ik,
    const float* __restrict__ r_jk, const float* __restrict__ mask,
    const float* __restrict__ etas, const float* __restrict__ zetas,
    float* __restrict__ out)
{
    __shared__ float  R2[T_TRIP];     // r2 per triple
    __shared__ float4 P[T_TRIP];      // w * bs^{zeta_j}
    __shared__ float  red[8][E_N][4]; // per-wave partial sums

    const int blk = blockIdx.x;            // flattened (b*N + n)
    const int tid = threadIdx.x;
    const size_t idx = (size_t)blk * T_TRIP + tid;

    const float z0 = zetas[0], z1 = zetas[1], z2 = zetas[2], z3 = zetas[3];
    const bool fastz = (z0 == 1.0f && z1 == 2.0f && z2 == 4.0f && z3 == 8.0f);
    const float PI_OVER_RC = 0.52359877559829887f;   // pi / 6

    // ---- Phase 1: one triple per thread ----
    {
        float a = r_ij[idx];
        float b = r_ik[idx];
        float c = r_jk[idx];
        float m = mask[idx];
        float r2 = fmaf(a, a, fmaf(b, b, c * c));
        float fa  = (a < 6.0f) ? 0.5f * (__cosf(a * PI_OVER_RC) + 1.0f) : 0.0f;
        float fb  = (b < 6.0f) ? 0.5f * (__cosf(b * PI_OVER_RC) + 1.0f) : 0.0f;
        float fcv = (c < 6.0f) ? 0.5f * (__cosf(c * PI_OVER_RC) + 1.0f) : 0.0f;
        float w = m * fa * fb * fcv;
        float ct = __fdividef(r2, 2.0f * a * b);
        float4 p;
        if (fastz) {
            float bs = 1.0f - ct;          // w==0 annihilates any magnitude
            float s2 = bs * bs, s4 = s2 * s2, s8 = s4 * s4;
            p = make_float4(w * bs, w * s2, w * s4, w * s8);
        } else {
            if (m == 0.0f) ct = 0.0f;      // powf(neg, frac) guard
            float bs = 1.0f - ct;
            p = make_float4(w * powf(bs, z0), w * powf(bs, z1),
                            w * powf(bs, z2), w * powf(bs, z3));
        }
        R2[tid] = r2;
        P[tid] = p;
    }
    __syncthreads();

    // ---- Phase 2: 32 groups of 16 lanes; lane = eta index e ----
    const int g = tid >> 4;          // group 0..31, handles t == g (mod 32)
    const int e = tid & 15;
    const float me = -etas[e];

    float acc0 = 0.0f, acc1 = 0.0f, acc2 = 0.0f, acc3 = 0.0f;
    #pragma unroll
    for (int i = 0; i < T_TRIP / 32; ++i) {
        int t = (i << 5) + g;
        float x = __expf(R2[t] * me);   // broadcast b32 + v_mul + v_exp
        float4 p = P[t];                // broadcast b128, conflict-free
        acc0 = fmaf(x, p.x, acc0);
        acc1 = fmaf(x, p.y, acc1);
        acc2 = fmaf(x, p.z, acc2);
        acc3 = fmaf(x, p.w, acc3);
    }

    // reduce the 4 groups within each wave (lanes l, l+16, l+32, l+48)
    acc0 += __shfl_down(acc0, 32); acc0 += __shfl_down(acc0, 16);
    acc1 += __shfl_down(acc1, 32); acc1 += __shfl_down(acc1, 16);
    acc2 += __shfl_down(acc2, 32); acc2 += __shfl_down(acc2, 16);
    acc3 += __shfl_down(acc3, 32); acc3 += __shfl_down(acc3, 16);

    const int wave = tid >> 6;       // 0..7
    if ((tid & 63) < 16) {
        red[wave][e][0] = acc0;
        red[wave][e][1] = acc1;
        red[wave][e][2] = acc2;
        red[wave][e][3] = acc3;
    }
    __syncthreads();

    // ---- Epilogue: combine 8 wave partials, apply 2^(1±zeta) ----
    if (tid < 128) {
        int ee = tid >> 3, z = tid & 7, j = z & 3;
        float s = 0.0f;
        #pragma unroll
        for (int wv = 0; wv < 8; ++wv) s += red[wv][ee][j];
        float zj = zetas[j];
        float coef = exp2f((z < 4) ? (1.0f - zj) : (1.0f + zj));
        out[(size_t)blk * 128 + tid] = coef * s;
    }
}

extern "C" void kernel_launch(void* const* d_in, const int* in_sizes, int n_in,
                              void* d_out, int out_size, void* d_ws, size_t ws_size,
                              hipStream_t stream) {
    const float* r_ij = (const float*)d_in[0];
    const float* r_ik = (const float*)d_in[1];
    const float* r_jk = (const float*)d_in[2];
    const float* mask = (const float*)d_in[3];
    const float* etas = (const float*)d_in[4];
    const float* zetas = (const float*)d_in[5];
    float* out = (float*)d_out;

    int nblk = out_size / 128;   // B*N rows, 128 outputs each
    behler_g2_kernel<<<nblk, 512, 0, stream>>>(r_ij, r_ik, r_jk, mask,
                                               etas, zetas, out);
}